// Round 4
// baseline (79.652 us; speedup 1.0000x reference)
//
#include <hip/hip_runtime.h>

#define BINS 10
#define TPB  256
#define NB_MAX 2048

// Pass 1: per-bin {count, sum-of-BCE} over valid elements.
// - register-resident sums (10-wide compare-select chain, static indices)
// - counts in two u64s, five 12-bit fields each (even bins / odd bins):
//   no drain logic; per-thread per-bin count <= 4095 holds for any n < 2^31
//   given grid*TPB = 524288 threads.
// - 2-stage software-pipelined loads (next quad in flight under current proc)
// - epilogue: 4-level shfl_xor (16-lane groups) + 1.28 KB LDS finish,
//   partials to d_ws (layout part[20][nb], coalesced for pass 2).
__global__ __launch_bounds__(TPB, 8) void ghmc_hist_kernel(
    const float4* __restrict__ pred4,
    const int4*   __restrict__ tgt4,
    const int4*   __restrict__ lw4,
    float* __restrict__ part,      // [2*BINS][nb]
    int n4, int n, int nb)
{
    float acc_s[BINS];
#pragma unroll
    for (int b = 0; b < BINS; ++b) acc_s[b] = 0.f;
    unsigned long long cA = 0ull, cB = 0ull;   // even-bin / odd-bin counters

    auto proc = [&](float p, int t, int w) {
        // q = t ? -p : p  ==>  g = sigmoid(q), bce = softplus(q)
        float q   = __int_as_float(__float_as_int(p) ^ (int)((unsigned)t << 31));
        float e   = __expf(-fabsf(q));            // exp(-|q|) in (0,1]
        float d   = 1.f + e;
        float r   = __builtin_amdgcn_rcpf(d);
        float sig = (q >= 0.f) ? r : e * r;       // sigmoid(q) == g in [0,1]
        int bin   = (int)(sig * 10.f);
        bin = bin > (BINS - 1) ? (BINS - 1) : bin;
        bool valid = (w > 0);
        float bce = fmaxf(q, 0.f) + __logf(d);    // softplus(q)
        int binm  = valid ? bin : 255;            // invalid matches no bin
#pragma unroll
        for (int b = 0; b < BINS; ++b)
            acc_s[b] += (binm == b) ? bce : 0.f;
        unsigned long long inc = valid ? (1ull << (12 * (bin >> 1))) : 0ull;
        bool odd = (bin & 1) != 0;
        cA += odd ? 0ull : inc;
        cB += odd ? inc  : 0ull;
    };

    const int tid    = threadIdx.x;
    const int stride = gridDim.x * TPB;

    // 2-stage pipelined grid-stride over float4 quads
    int iA = blockIdx.x * TPB + tid;
    bool vA = iA < n4;
    float4 pA; int4 tA, wA;
    if (vA) { pA = pred4[iA]; tA = tgt4[iA]; wA = lw4[iA]; }
    while (vA) {
        const int iB = iA + stride;
        const bool vB = iB < n4;
        float4 pB; int4 tB, wB;
        if (vB) { pB = pred4[iB]; tB = tgt4[iB]; wB = lw4[iB]; }

        proc(pA.x, tA.x, wA.x); proc(pA.y, tA.y, wA.y);
        proc(pA.z, tA.z, wA.z); proc(pA.w, tA.w, wA.w);

        iA = iB + stride;
        vA = iA < n4;
        if (vA) { pA = pred4[iA]; tA = tgt4[iA]; wA = lw4[iA]; }

        if (vB) {
            proc(pB.x, tB.x, wB.x); proc(pB.y, tB.y, wB.y);
            proc(pB.z, tB.z, wB.z); proc(pB.w, tB.w, wB.w);
        }
    }
    // scalar tail (n not divisible by 4)
    {
        const float* predf = (const float*)pred4;
        const int*   tgtf  = (const int*)tgt4;
        const int*   lwf   = (const int*)lw4;
        for (int j = n4 * 4 + blockIdx.x * TPB + tid; j < n; j += stride)
            proc(predf[j], tgtf[j], lwf[j]);
    }

    // unpack counts to floats (exact: integers < 4096)
    float cnt[BINS];
#pragma unroll
    for (int b = 0; b < BINS; ++b) {
        unsigned long long pk = (b & 1) ? cB : cA;
        cnt[b] = (float)((pk >> (12 * (b >> 1))) & 0xFFFull);
    }

    // 4-level xor reduce within 16-lane groups (DPP-friendly offsets)
#pragma unroll
    for (int b = 0; b < BINS; ++b) {
#pragma unroll
        for (int off = 1; off <= 8; off <<= 1) {
            acc_s[b] += __shfl_xor(acc_s[b], off, 64);
            cnt[b]   += __shfl_xor(cnt[b],   off, 64);
        }
    }

    // 16 group leaders -> tiny LDS -> 20 threads finish the block partials
    __shared__ float red[2 * BINS][16];   // 1.28 KB
    const int grp = tid >> 4;
    if ((tid & 15) == 0) {
#pragma unroll
        for (int b = 0; b < BINS; ++b) {
            red[b][grp]        = acc_s[b];
            red[BINS + b][grp] = cnt[b];
        }
    }
    __syncthreads();
    if (tid < 2 * BINS) {
        float v = 0.f;
#pragma unroll
        for (int g = 0; g < 16; ++g) v += red[tid][g];
        part[tid * nb + blockIdx.x] = v;
    }
}

// Pass 2: reduce nb partials per row (coalesced), compute the scalar loss.
__global__ __launch_bounds__(TPB) void ghmc_final_kernel(
    const float* __restrict__ part, float* __restrict__ out, int nb)
{
    __shared__ float sh[2 * BINS][4];
    const int tid  = threadIdx.x;
    const int lane = tid & 63;
    const int wv   = tid >> 6;

#pragma unroll
    for (int v = 0; v < 2 * BINS; ++v) {
        float s = 0.f;
        for (int i = tid; i < nb; i += TPB) s += part[v * nb + i];
#pragma unroll
        for (int off = 32; off >= 1; off >>= 1) s += __shfl_xor(s, off, 64);
        if (lane == 0) sh[v][wv] = s;
    }
    __syncthreads();

    if (tid == 0) {
        float sums[BINS], cnts[BINS];
        float ti = 0.f; int nbn = 0;
#pragma unroll
        for (int b = 0; b < BINS; ++b) {
            sums[b] = sh[b][0] + sh[b][1] + sh[b][2] + sh[b][3];
            cnts[b] = sh[BINS + b][0] + sh[BINS + b][1] + sh[BINS + b][2] + sh[BINS + b][3];
            ti += cnts[b];
            nbn += (cnts[b] > 0.f) ? 1 : 0;
        }
        float total = fmaxf(ti, 1.f);
        float nf    = (float)(nbn > 0 ? nbn : 1);
        float loss  = 0.f;
#pragma unroll
        for (int b = 0; b < BINS; ++b) {
            if (cnts[b] > 0.f) {
                float w = (total / cnts[b]) / nf;   // w_bin[b]
                loss += w * sums[b];
            }
        }
        out[0] = loss / total * 1.0f;  // LOSS_WEIGHT = 1.0
    }
}

extern "C" void kernel_launch(void* const* d_in, const int* in_sizes, int n_in,
                              void* d_out, int out_size, void* d_ws, size_t ws_size,
                              hipStream_t stream)
{
    const float4* pred4 = (const float4*)d_in[0];
    const int4*   tgt4  = (const int4*)d_in[1];
    const int4*   lw4   = (const int4*)d_in[2];

    const int n  = in_sizes[0];
    const int n4 = n / 4;

    int nb = (n4 + TPB - 1) / TPB;
    if (nb > NB_MAX) nb = NB_MAX;
    int ws_cap = (int)(ws_size / (2 * BINS * sizeof(float)));
    if (nb > ws_cap) nb = ws_cap;
    if (nb < 1) nb = 1;

    float* part = (float*)d_ws;   // [2*BINS][nb]

    ghmc_hist_kernel<<<nb, TPB, 0, stream>>>(pred4, tgt4, lw4, part, n4, n, nb);
    ghmc_final_kernel<<<1, TPB, 0, stream>>>(part, (float*)d_out, nb);
}

// Round 5
// 45.071 us; speedup vs baseline: 1.7672x; 1.7672x over previous
//
#include <hip/hip_runtime.h>

#define BINS 10
#define TPB  256
#define NB_MAX 2048
#define FTPB 1024   // finalize block size

// Pass 1: per-bin {count, sum-of-BCE} over valid elements.
// - register-resident sums (10-wide compare-select chain, static indices)
// - counts in two u64s, five 12-bit fields each (even bins / odd bins)
// - 2-stage software-pipelined loads (next quad in flight under current proc)
// - epilogue: 4-level shfl_xor (16-lane groups) + 1.28 KB LDS finish.
// Partials written as ONE CONTIGUOUS 20-float record per block:
//   part[bid*20 + v], so pass 2 can read records with independent float4s.
__global__ __launch_bounds__(TPB, 8) void ghmc_hist_kernel(
    const float4* __restrict__ pred4,
    const int4*   __restrict__ tgt4,
    const int4*   __restrict__ lw4,
    float* __restrict__ part,      // [nb][2*BINS]
    int n4, int n)
{
    float acc_s[BINS];
#pragma unroll
    for (int b = 0; b < BINS; ++b) acc_s[b] = 0.f;
    unsigned long long cA = 0ull, cB = 0ull;   // even-bin / odd-bin counters

    auto proc = [&](float p, int t, int w) {
        // q = t ? -p : p  ==>  g = sigmoid(q), bce = softplus(q)
        float q   = __int_as_float(__float_as_int(p) ^ (int)((unsigned)t << 31));
        float e   = __expf(-fabsf(q));            // exp(-|q|) in (0,1]
        float d   = 1.f + e;
        float r   = __builtin_amdgcn_rcpf(d);
        float sig = (q >= 0.f) ? r : e * r;       // sigmoid(q) == g in [0,1]
        int bin   = (int)(sig * 10.f);
        bin = bin > (BINS - 1) ? (BINS - 1) : bin;
        bool valid = (w > 0);
        float bce = fmaxf(q, 0.f) + __logf(d);    // softplus(q)
        int binm  = valid ? bin : 255;            // invalid matches no bin
#pragma unroll
        for (int b = 0; b < BINS; ++b)
            acc_s[b] += (binm == b) ? bce : 0.f;
        unsigned long long inc = valid ? (1ull << (12 * (bin >> 1))) : 0ull;
        bool odd = (bin & 1) != 0;
        cA += odd ? 0ull : inc;
        cB += odd ? inc  : 0ull;
    };

    const int tid    = threadIdx.x;
    const int stride = gridDim.x * TPB;

    // 2-stage pipelined grid-stride over float4 quads
    int iA = blockIdx.x * TPB + tid;
    bool vA = iA < n4;
    float4 pA; int4 tA, wA;
    if (vA) { pA = pred4[iA]; tA = tgt4[iA]; wA = lw4[iA]; }
    while (vA) {
        const int iB = iA + stride;
        const bool vB = iB < n4;
        float4 pB; int4 tB, wB;
        if (vB) { pB = pred4[iB]; tB = tgt4[iB]; wB = lw4[iB]; }

        proc(pA.x, tA.x, wA.x); proc(pA.y, tA.y, wA.y);
        proc(pA.z, tA.z, wA.z); proc(pA.w, tA.w, wA.w);

        iA = iB + stride;
        vA = iA < n4;
        if (vA) { pA = pred4[iA]; tA = tgt4[iA]; wA = lw4[iA]; }

        if (vB) {
            proc(pB.x, tB.x, wB.x); proc(pB.y, tB.y, wB.y);
            proc(pB.z, tB.z, wB.z); proc(pB.w, tB.w, wB.w);
        }
    }
    // scalar tail (n not divisible by 4)
    {
        const float* predf = (const float*)pred4;
        const int*   tgtf  = (const int*)tgt4;
        const int*   lwf   = (const int*)lw4;
        for (int j = n4 * 4 + blockIdx.x * TPB + tid; j < n; j += stride)
            proc(predf[j], tgtf[j], lwf[j]);
    }

    // unpack counts to floats (exact: integers < 4096)
    float cnt[BINS];
#pragma unroll
    for (int b = 0; b < BINS; ++b) {
        unsigned long long pk = (b & 1) ? cB : cA;
        cnt[b] = (float)((pk >> (12 * (b >> 1))) & 0xFFFull);
    }

    // 4-level xor reduce within 16-lane groups (DPP-friendly offsets)
#pragma unroll
    for (int b = 0; b < BINS; ++b) {
#pragma unroll
        for (int off = 1; off <= 8; off <<= 1) {
            acc_s[b] += __shfl_xor(acc_s[b], off, 64);
            cnt[b]   += __shfl_xor(cnt[b],   off, 64);
        }
    }

    // 16 group leaders -> tiny LDS -> 20 threads finish the block partials
    __shared__ float red[2 * BINS][16];   // 1.28 KB
    const int grp = tid >> 4;
    if ((tid & 15) == 0) {
#pragma unroll
        for (int b = 0; b < BINS; ++b) {
            red[b][grp]        = acc_s[b];
            red[BINS + b][grp] = cnt[b];
        }
    }
    __syncthreads();
    if (tid < 2 * BINS) {
        float v = 0.f;
#pragma unroll
        for (int g = 0; g < 16; ++g) v += red[tid][g];
        part[blockIdx.x * (2 * BINS) + tid] = v;   // contiguous record
    }
}

// Pass 2: reduce nb 20-float records with full ILP, compute the scalar loss.
// 1024 threads; each thread reads its records via 5 independent float4 loads.
__global__ __launch_bounds__(FTPB) void ghmc_final_kernel(
    const float* __restrict__ part, float* __restrict__ out, int nb)
{
    float acc[2 * BINS];
#pragma unroll
    for (int v = 0; v < 2 * BINS; ++v) acc[v] = 0.f;

    const int tid = threadIdx.x;
    for (int i = tid; i < nb; i += FTPB) {
        const float4* rec = (const float4*)(part + (size_t)i * (2 * BINS));
        float4 a = rec[0], b = rec[1], c = rec[2], d = rec[3], e = rec[4];
        acc[0]  += a.x; acc[1]  += a.y; acc[2]  += a.z; acc[3]  += a.w;
        acc[4]  += b.x; acc[5]  += b.y; acc[6]  += b.z; acc[7]  += b.w;
        acc[8]  += c.x; acc[9]  += c.y; acc[10] += c.z; acc[11] += c.w;
        acc[12] += d.x; acc[13] += d.y; acc[14] += d.z; acc[15] += d.w;
        acc[16] += e.x; acc[17] += e.y; acc[18] += e.z; acc[19] += e.w;
    }

    // full 64-lane xor reduce
#pragma unroll
    for (int v = 0; v < 2 * BINS; ++v) {
#pragma unroll
        for (int off = 1; off <= 32; off <<= 1)
            acc[v] += __shfl_xor(acc[v], off, 64);
    }

    __shared__ float sh[2 * BINS][16];
    const int wv = tid >> 6, lane = tid & 63;
    if (lane == 0) {
#pragma unroll
        for (int v = 0; v < 2 * BINS; ++v) sh[v][wv] = acc[v];
    }
    __syncthreads();
    if (tid < 2 * BINS) {
        float s = 0.f;
#pragma unroll
        for (int g = 0; g < 16; ++g) s += sh[tid][g];
        sh[tid][0] = s;
    }
    __syncthreads();

    if (tid == 0) {
        float ti = 0.f; int nbn = 0;
        float cnts[BINS];
#pragma unroll
        for (int b = 0; b < BINS; ++b) {
            cnts[b] = sh[BINS + b][0];
            ti += cnts[b];
            nbn += (cnts[b] > 0.f) ? 1 : 0;
        }
        float total = fmaxf(ti, 1.f);
        float nf    = (float)(nbn > 0 ? nbn : 1);
        float loss  = 0.f;
#pragma unroll
        for (int b = 0; b < BINS; ++b) {
            if (cnts[b] > 0.f) {
                float w = (total / cnts[b]) / nf;   // w_bin[b]
                loss += w * sh[b][0];
            }
        }
        out[0] = loss / total * 1.0f;  // LOSS_WEIGHT = 1.0
    }
}

extern "C" void kernel_launch(void* const* d_in, const int* in_sizes, int n_in,
                              void* d_out, int out_size, void* d_ws, size_t ws_size,
                              hipStream_t stream)
{
    const float4* pred4 = (const float4*)d_in[0];
    const int4*   tgt4  = (const int4*)d_in[1];
    const int4*   lw4   = (const int4*)d_in[2];

    const int n  = in_sizes[0];
    const int n4 = n / 4;

    int nb = (n4 + TPB - 1) / TPB;
    if (nb > NB_MAX) nb = NB_MAX;
    int ws_cap = (int)(ws_size / (2 * BINS * sizeof(float)));
    if (nb > ws_cap) nb = ws_cap;
    if (nb < 1) nb = 1;

    float* part = (float*)d_ws;   // [nb][2*BINS]

    ghmc_hist_kernel<<<nb, TPB, 0, stream>>>(pred4, tgt4, lw4, part, n4, n);
    ghmc_final_kernel<<<1, FTPB, 0, stream>>>(part, (float*)d_out, nb);
}

// Round 6
// 40.967 us; speedup vs baseline: 1.9443x; 1.1002x over previous
//
#include <hip/hip_runtime.h>

#define BINS 10
#define TPB  256
#define NB_MAX 2048
#define FTPB 1024   // finalize block size

// Pass 1: per-bin {count, sum-of-BCE} over valid elements.
// - register-resident sums (10-wide compare-select chain, static indices)
// - counts in two u64s, five 12-bit fields each (even bins / odd bins)
// - 2-stage software-pipelined loads (next quad in flight under current proc)
// - __launch_bounds__(256, 4): 128-VGPR budget -- the pipeline state (~70
//   VGPRs) must stay in registers; the (256,8)/64-VGPR version spilled ~31 MB
//   of scratch traffic per launch and was latency-bound on the spills.
// - epilogue: 4-level shfl_xor (16-lane groups) + 1.28 KB LDS finish.
// Partials written as ONE CONTIGUOUS 20-float record per block.
__global__ __launch_bounds__(TPB, 4) void ghmc_hist_kernel(
    const float4* __restrict__ pred4,
    const int4*   __restrict__ tgt4,
    const int4*   __restrict__ lw4,
    float* __restrict__ part,      // [nb][2*BINS]
    int n4, int n)
{
    float acc_s[BINS];
#pragma unroll
    for (int b = 0; b < BINS; ++b) acc_s[b] = 0.f;
    unsigned long long cA = 0ull, cB = 0ull;   // even-bin / odd-bin counters

    auto proc = [&](float p, int t, int w) {
        // q = t ? -p : p  ==>  g = sigmoid(q), bce = softplus(q)
        float q   = __int_as_float(__float_as_int(p) ^ (int)((unsigned)t << 31));
        float e   = __expf(-fabsf(q));            // exp(-|q|) in (0,1]
        float d   = 1.f + e;
        float r   = __builtin_amdgcn_rcpf(d);
        float sig = (q >= 0.f) ? r : e * r;       // sigmoid(q) == g in [0,1]
        int bin   = (int)(sig * 10.f);
        bin = bin > (BINS - 1) ? (BINS - 1) : bin;
        bool valid = (w > 0);
        float bce = fmaxf(q, 0.f) + __logf(d);    // softplus(q)
        int binm  = valid ? bin : 255;            // invalid matches no bin
#pragma unroll
        for (int b = 0; b < BINS; ++b)
            acc_s[b] += (binm == b) ? bce : 0.f;
        unsigned long long inc = valid ? (1ull << (12 * (bin >> 1))) : 0ull;
        bool odd = (bin & 1) != 0;
        cA += odd ? 0ull : inc;
        cB += odd ? inc  : 0ull;
    };

    const int tid    = threadIdx.x;
    const int stride = gridDim.x * TPB;

    // 2-stage pipelined grid-stride over float4 quads
    int iA = blockIdx.x * TPB + tid;
    bool vA = iA < n4;
    float4 pA; int4 tA, wA;
    if (vA) { pA = pred4[iA]; tA = tgt4[iA]; wA = lw4[iA]; }
    while (vA) {
        const int iB = iA + stride;
        const bool vB = iB < n4;
        float4 pB; int4 tB, wB;
        if (vB) { pB = pred4[iB]; tB = tgt4[iB]; wB = lw4[iB]; }

        proc(pA.x, tA.x, wA.x); proc(pA.y, tA.y, wA.y);
        proc(pA.z, tA.z, wA.z); proc(pA.w, tA.w, wA.w);

        iA = iB + stride;
        vA = iA < n4;
        if (vA) { pA = pred4[iA]; tA = tgt4[iA]; wA = lw4[iA]; }

        if (vB) {
            proc(pB.x, tB.x, wB.x); proc(pB.y, tB.y, wB.y);
            proc(pB.z, tB.z, wB.z); proc(pB.w, tB.w, wB.w);
        }
    }
    // scalar tail (n not divisible by 4)
    {
        const float* predf = (const float*)pred4;
        const int*   tgtf  = (const int*)tgt4;
        const int*   lwf   = (const int*)lw4;
        for (int j = n4 * 4 + blockIdx.x * TPB + tid; j < n; j += stride)
            proc(predf[j], tgtf[j], lwf[j]);
    }

    // unpack counts to floats (exact: integers < 4096)
    float cnt[BINS];
#pragma unroll
    for (int b = 0; b < BINS; ++b) {
        unsigned long long pk = (b & 1) ? cB : cA;
        cnt[b] = (float)((pk >> (12 * (b >> 1))) & 0xFFFull);
    }

    // 4-level xor reduce within 16-lane groups (DPP-friendly offsets)
#pragma unroll
    for (int b = 0; b < BINS; ++b) {
#pragma unroll
        for (int off = 1; off <= 8; off <<= 1) {
            acc_s[b] += __shfl_xor(acc_s[b], off, 64);
            cnt[b]   += __shfl_xor(cnt[b],   off, 64);
        }
    }

    // 16 group leaders -> tiny LDS -> 20 threads finish the block partials
    __shared__ float red[2 * BINS][16];   // 1.28 KB
    const int grp = tid >> 4;
    if ((tid & 15) == 0) {
#pragma unroll
        for (int b = 0; b < BINS; ++b) {
            red[b][grp]        = acc_s[b];
            red[BINS + b][grp] = cnt[b];
        }
    }
    __syncthreads();
    if (tid < 2 * BINS) {
        float v = 0.f;
#pragma unroll
        for (int g = 0; g < 16; ++g) v += red[tid][g];
        part[blockIdx.x * (2 * BINS) + tid] = v;   // contiguous record
    }
}

// Pass 2: reduce nb 20-float records with full ILP, compute the scalar loss.
// 1024 threads; each thread reads its records via 5 independent float4 loads.
__global__ __launch_bounds__(FTPB) void ghmc_final_kernel(
    const float* __restrict__ part, float* __restrict__ out, int nb)
{
    float acc[2 * BINS];
#pragma unroll
    for (int v = 0; v < 2 * BINS; ++v) acc[v] = 0.f;

    const int tid = threadIdx.x;
    for (int i = tid; i < nb; i += FTPB) {
        const float4* rec = (const float4*)(part + (size_t)i * (2 * BINS));
        float4 a = rec[0], b = rec[1], c = rec[2], d = rec[3], e = rec[4];
        acc[0]  += a.x; acc[1]  += a.y; acc[2]  += a.z; acc[3]  += a.w;
        acc[4]  += b.x; acc[5]  += b.y; acc[6]  += b.z; acc[7]  += b.w;
        acc[8]  += c.x; acc[9]  += c.y; acc[10] += c.z; acc[11] += c.w;
        acc[12] += d.x; acc[13] += d.y; acc[14] += d.z; acc[15] += d.w;
        acc[16] += e.x; acc[17] += e.y; acc[18] += e.z; acc[19] += e.w;
    }

    // full 64-lane xor reduce
#pragma unroll
    for (int v = 0; v < 2 * BINS; ++v) {
#pragma unroll
        for (int off = 1; off <= 32; off <<= 1)
            acc[v] += __shfl_xor(acc[v], off, 64);
    }

    __shared__ float sh[2 * BINS][16];
    const int wv = tid >> 6, lane = tid & 63;
    if (lane == 0) {
#pragma unroll
        for (int v = 0; v < 2 * BINS; ++v) sh[v][wv] = acc[v];
    }
    __syncthreads();
    if (tid < 2 * BINS) {
        float s = 0.f;
#pragma unroll
        for (int g = 0; g < 16; ++g) s += sh[tid][g];
        sh[tid][0] = s;
    }
    __syncthreads();

    if (tid == 0) {
        float ti = 0.f; int nbn = 0;
        float cnts[BINS];
#pragma unroll
        for (int b = 0; b < BINS; ++b) {
            cnts[b] = sh[BINS + b][0];
            ti += cnts[b];
            nbn += (cnts[b] > 0.f) ? 1 : 0;
        }
        float total = fmaxf(ti, 1.f);
        float nf    = (float)(nbn > 0 ? nbn : 1);
        float loss  = 0.f;
#pragma unroll
        for (int b = 0; b < BINS; ++b) {
            if (cnts[b] > 0.f) {
                float w = (total / cnts[b]) / nf;   // w_bin[b]
                loss += w * sh[b][0];
            }
        }
        out[0] = loss / total * 1.0f;  // LOSS_WEIGHT = 1.0
    }
}

extern "C" void kernel_launch(void* const* d_in, const int* in_sizes, int n_in,
                              void* d_out, int out_size, void* d_ws, size_t ws_size,
                              hipStream_t stream)
{
    const float4* pred4 = (const float4*)d_in[0];
    const int4*   tgt4  = (const int4*)d_in[1];
    const int4*   lw4   = (const int4*)d_in[2];

    const int n  = in_sizes[0];
    const int n4 = n / 4;

    int nb = (n4 + TPB - 1) / TPB;
    if (nb > NB_MAX) nb = NB_MAX;
    int ws_cap = (int)(ws_size / (2 * BINS * sizeof(float)));
    if (nb > ws_cap) nb = ws_cap;
    if (nb < 1) nb = 1;

    float* part = (float*)d_ws;   // [nb][2*BINS]

    ghmc_hist_kernel<<<nb, TPB, 0, stream>>>(pred4, tgt4, lw4, part, n4, n);
    ghmc_final_kernel<<<1, FTPB, 0, stream>>>(part, (float*)d_out, nb);
}

// Round 7
// 38.547 us; speedup vs baseline: 2.0664x; 1.0628x over previous
//
#include <hip/hip_runtime.h>

#define BINS 10
#define TPB  256
#define NB_MAX 2048
#define FTPB 1024   // finalize block size
#define KPACK 4096.0f

// Pass 1: per-bin (count,sum) fused into ONE accumulator per bin:
//   acc[b] += (bin==b) ? (bce + 4096) : 0
// Per-thread S_b < 160 << 4096, so epilogue separation C=floor(acc/4096),
// S=acc-4096*C is exact to ~1e-5 relative. This deletes the u64 counter path.
// One-hot selection is VCC-free: bit=1<<bin, sel=bfe_i32(bit,b,1) in {0,-1},
// acc[b] += sel & v  (3 plain VALU ops per bin, fully parallel).
// Uniform trip-count loop (no per-quad branches) + 2-stage pipelined loads.
__global__ __launch_bounds__(TPB, 4) void ghmc_hist_kernel(
    const float4* __restrict__ pred4,
    const int4*   __restrict__ tgt4,
    const int4*   __restrict__ lw4,
    float* __restrict__ part,      // [nb][2*BINS]
    int n4, int n)
{
    float acc[BINS];
#pragma unroll
    for (int b = 0; b < BINS; ++b) acc[b] = 0.f;

    auto proc = [&](float p, int t, int w) {
        // q = t ? -p : p  ==>  sigmoid(q) = g,  softplus(q) = bce
        float q    = __int_as_float(__float_as_int(p) ^ (t << 31));
        float e    = __expf(-fabsf(q));           // exp(-|q|) in (0,1]
        float d    = 1.f + e;
        float r    = __builtin_amdgcn_rcpf(d);
        float num  = (q >= 0.f) ? 1.0f : e;       // sigmoid numerator
        float sig10 = num * (10.f * r);           // 10*sigmoid(q) in [0,10]
        int bin    = (int)sig10;
        bin = bin > (BINS - 1) ? (BINS - 1) : bin;
        float bce  = fmaxf(q, 0.f) + __logf(d);   // softplus(q)
        float v    = (w > 0) ? (bce + KPACK) : 0.f;
        int bit    = 1 << bin;
        int vbits  = __float_as_int(v);
#pragma unroll
        for (int b = 0; b < BINS; ++b) {
            int sel = ((int)((unsigned)bit << (31 - b))) >> 31;  // v_bfe_i32
            acc[b] += __int_as_float(sel & vbits);
        }
    };

    const int tid    = threadIdx.x;
    const int stride = gridDim.x * TPB;
    const int base   = blockIdx.x * TPB + tid;

    // uniform main-loop trip count (identical for every thread in the grid)
    const int full = n4 / stride;

    int i = base;
    float4 pA; int4 tA, wA;
    if (full > 0) { pA = pred4[i]; tA = tgt4[i]; wA = lw4[i]; }
#pragma unroll 2
    for (int k = 0; k < full - 1; ++k) {
        const int j = i + stride;
        float4 pB = pred4[j]; int4 tB = tgt4[j]; int4 wB = lw4[j];
        proc(pA.x, tA.x, wA.x); proc(pA.y, tA.y, wA.y);
        proc(pA.z, tA.z, wA.z); proc(pA.w, tA.w, wA.w);
        pA = pB; tA = tB; wA = wB;
        i = j;
    }
    if (full > 0) {
        proc(pA.x, tA.x, wA.x); proc(pA.y, tA.y, wA.y);
        proc(pA.z, tA.z, wA.z); proc(pA.w, tA.w, wA.w);
    }
    // remainder quad (threads with one extra quad)
    {
        const int j = base + full * stride;
        if (j < n4) {
            float4 p = pred4[j]; int4 t = tgt4[j]; int4 w = lw4[j];
            proc(p.x, t.x, w.x); proc(p.y, t.y, w.y);
            proc(p.z, t.z, w.z); proc(p.w, t.w, w.w);
        }
    }
    // scalar tail (n not divisible by 4): first n&3 threads of block 0
    if (blockIdx.x == 0 && tid < (n & 3)) {
        const float* predf = (const float*)pred4;
        const int*   tgtf  = (const int*)tgt4;
        const int*   lwf   = (const int*)lw4;
        const int j = n4 * 4 + tid;
        proc(predf[j], tgtf[j], lwf[j]);
    }

    // separate counts and sums (exact; see header comment)
    float s_[BINS], c_[BINS];
#pragma unroll
    for (int b = 0; b < BINS; ++b) {
        float Cf = floorf(acc[b] * (1.f / KPACK));
        c_[b] = Cf;
        s_[b] = acc[b] - KPACK * Cf;
    }

    // 4-level xor reduce within 16-lane groups
#pragma unroll
    for (int b = 0; b < BINS; ++b) {
#pragma unroll
        for (int off = 1; off <= 8; off <<= 1) {
            s_[b] += __shfl_xor(s_[b], off, 64);
            c_[b] += __shfl_xor(c_[b], off, 64);
        }
    }

    // 16 group leaders -> tiny LDS -> 20 threads write the block record
    __shared__ float red[2 * BINS][16];   // 1.28 KB
    const int grp = tid >> 4;
    if ((tid & 15) == 0) {
#pragma unroll
        for (int b = 0; b < BINS; ++b) {
            red[b][grp]        = s_[b];
            red[BINS + b][grp] = c_[b];
        }
    }
    __syncthreads();
    if (tid < 2 * BINS) {
        float v = 0.f;
#pragma unroll
        for (int g = 0; g < 16; ++g) v += red[tid][g];
        part[blockIdx.x * (2 * BINS) + tid] = v;   // contiguous record
    }
}

// Pass 2: reduce nb 20-float records with full ILP, compute the scalar loss.
__global__ __launch_bounds__(FTPB) void ghmc_final_kernel(
    const float* __restrict__ part, float* __restrict__ out, int nb)
{
    float acc[2 * BINS];
#pragma unroll
    for (int v = 0; v < 2 * BINS; ++v) acc[v] = 0.f;

    const int tid = threadIdx.x;
    for (int i = tid; i < nb; i += FTPB) {
        const float4* rec = (const float4*)(part + (size_t)i * (2 * BINS));
        float4 a = rec[0], b = rec[1], c = rec[2], d = rec[3], e = rec[4];
        acc[0]  += a.x; acc[1]  += a.y; acc[2]  += a.z; acc[3]  += a.w;
        acc[4]  += b.x; acc[5]  += b.y; acc[6]  += b.z; acc[7]  += b.w;
        acc[8]  += c.x; acc[9]  += c.y; acc[10] += c.z; acc[11] += c.w;
        acc[12] += d.x; acc[13] += d.y; acc[14] += d.z; acc[15] += d.w;
        acc[16] += e.x; acc[17] += e.y; acc[18] += e.z; acc[19] += e.w;
    }

#pragma unroll
    for (int v = 0; v < 2 * BINS; ++v) {
#pragma unroll
        for (int off = 1; off <= 32; off <<= 1)
            acc[v] += __shfl_xor(acc[v], off, 64);
    }

    __shared__ float sh[2 * BINS][16];
    const int wv = tid >> 6, lane = tid & 63;
    if (lane == 0) {
#pragma unroll
        for (int v = 0; v < 2 * BINS; ++v) sh[v][wv] = acc[v];
    }
    __syncthreads();
    if (tid < 2 * BINS) {
        float s = 0.f;
#pragma unroll
        for (int g = 0; g < 16; ++g) s += sh[tid][g];
        sh[tid][0] = s;
    }
    __syncthreads();

    if (tid == 0) {
        float ti = 0.f; int nbn = 0;
        float cnts[BINS];
#pragma unroll
        for (int b = 0; b < BINS; ++b) {
            cnts[b] = sh[BINS + b][0];
            ti += cnts[b];
            nbn += (cnts[b] > 0.f) ? 1 : 0;
        }
        float total = fmaxf(ti, 1.f);
        float nf    = (float)(nbn > 0 ? nbn : 1);
        float loss  = 0.f;
#pragma unroll
        for (int b = 0; b < BINS; ++b) {
            if (cnts[b] > 0.f) {
                float w = (total / cnts[b]) / nf;   // w_bin[b]
                loss += w * sh[b][0];
            }
        }
        out[0] = loss / total * 1.0f;  // LOSS_WEIGHT = 1.0
    }
}

extern "C" void kernel_launch(void* const* d_in, const int* in_sizes, int n_in,
                              void* d_out, int out_size, void* d_ws, size_t ws_size,
                              hipStream_t stream)
{
    const float4* pred4 = (const float4*)d_in[0];
    const int4*   tgt4  = (const int4*)d_in[1];
    const int4*   lw4   = (const int4*)d_in[2];

    const int n  = in_sizes[0];
    const int n4 = n / 4;

    int nb = (n4 + TPB - 1) / TPB;
    if (nb > NB_MAX) nb = NB_MAX;
    int ws_cap = (int)(ws_size / (2 * BINS * sizeof(float)));
    if (nb > ws_cap) nb = ws_cap;
    if (nb < 1) nb = 1;

    float* part = (float*)d_ws;   // [nb][2*BINS]

    ghmc_hist_kernel<<<nb, TPB, 0, stream>>>(pred4, tgt4, lw4, part, n4, n);
    ghmc_final_kernel<<<1, FTPB, 0, stream>>>(part, (float*)d_out, nb);
}